// Round 10
// baseline (29.486 us; speedup 1.0000x reference)
//
#include <hip/hip_runtime.h>
#include <math.h>

#define IN_SIZE 448
#define OUT_SIZE 224
#define PLANE (IN_SIZE * IN_SIZE)
#define PX_PER_SAMPLE (OUT_SIZE * OUT_SIZE)   // 50176
#define BLOCKS_PER_SAMPLE (PX_PER_SAMPLE / 256) // 196

// jax.nn.sigmoid(10*d) at INTEGER d, branchless 5-case select.
// Exact f32 for |d|<=1; abs error < 2.1e-9 elsewhere.
__device__ __forceinline__ float sig10i(int d) {
    const float neg = (d == -1) ? 4.5397868e-5f : 2.0611536e-9f;
    const float pos = (d == 0) ? 0.5f : ((d == 1) ? 0.99995458f : 1.0f);
    return (d < 0) ? neg : pos;
}

__global__ __launch_bounds__(256) void attention_crop_kernel(
    const float* __restrict__ images,   // [B,3,448,448]
    const float* __restrict__ locs,     // [B,3]
    float* __restrict__ out)            // [B,3,224,224]
{
    // XCD chunk swizzle: each XCD gets a contiguous chunk of samples
    // (per-sample 2.4 MB fits the 4 MB per-XCD L2). grid % 8 == 0.
    const int cpx = gridDim.x >> 3;
    const int bid = (blockIdx.x & 7) * cpx + (blockIdx.x >> 3);

    // b derived from blockIdx ONLY -> wave-uniform in the compiler's eyes:
    // locs[] reads become s_load (hoisted, off the VMEM path).
    const int b   = bid / BLOCKS_PER_SAMPLE;            // sample index (scalar)
    const int blk = bid - b * BLOCKS_PER_SAMPLE;
    const int px  = blk * 256 + threadIdx.x;            // 0..50175 within sample
    const int i   = px / OUT_SIZE;
    const int j   = px - i * OUT_SIZE;

    // ---- per-sample scalars (locs index is scalar -> SMEM load) ----
    float tx = locs[b * 3 + 0];
    float ty = locs[b * 3 + 1];
    float tl = locs[b * 3 + 2];
    const float third = 448.0f / 3.0f;
    tl = fmaxf(tl, third);
    tx = fminf(fmaxf(tx, tl), 448.0f - tl);
    ty = fminf(fmaxf(ty, tl), 448.0f - tl);

    const float w_off_f = fminf(fmaxf(floorf(tx - tl), 0.0f), 448.0f);
    const float h_off_f = fminf(fmaxf(floorf(ty - tl), 0.0f), 448.0f);
    const float w_end_f = fminf(fmaxf(floorf(tx + tl), 0.0f), 448.0f);
    const float h_end_f = fminf(fmaxf(floorf(ty + tl), 0.0f), 448.0f);
    const int w_off = (int)w_off_f;
    const int h_off = (int)h_off_f;
    const int w_end = (int)w_end_f;
    const int h_end = (int)h_end_f;

    // ---- sample coords; clamp-refactor so r1=r0+1, c1=c0+1 ALWAYS ----
    const float r = w_off_f + ((float)i / 223.0f) * (float)(w_end - 1 - w_off);
    const float c = h_off_f + ((float)j / 223.0f) * (float)(h_end - 1 - h_off);
    const int r0 = min((int)floorf(r), IN_SIZE - 2);
    const int c0 = min((int)floorf(c), IN_SIZE - 2);
    const float fr = r - (float)r0;
    const float fc = c - (float)c0;

    // ---- masks at the 4 taps (LUT) ----
    const float mr0 = sig10i(r0 - w_off)     - sig10i(r0 - w_end);
    const float mr1 = sig10i(r0 + 1 - w_off) - sig10i(r0 + 1 - w_end);
    const float mc0 = sig10i(c0 - h_off)     - sig10i(c0 - h_end);
    const float mc1 = sig10i(c0 + 1 - h_off) - sig10i(c0 + 1 - h_end);

    // ---- combined weight per tap (mask × bilinear), shared by 3 channels ----
    const float W00 = mr0 * mc0 * (1.0f - fc) * (1.0f - fr);
    const float W01 = mr0 * mc1 * fc * (1.0f - fr);
    const float W10 = mr1 * mc0 * (1.0f - fc) * fr;
    const float W11 = mr1 * mc1 * fc * fr;

    const size_t img_base = (size_t)b * 3 * PLANE + (size_t)r0 * IN_SIZE + c0;
    const size_t out_base = (size_t)b * 3 * OUT_SIZE * OUT_SIZE
                          + (size_t)i * OUT_SIZE + j;

#pragma unroll
    for (int ch = 0; ch < 3; ++ch) {
        const float* __restrict__ p = images + img_base + (size_t)ch * PLANE;
        float t[2], bt[2];                       // (v00,v01) and (v10,v11): adjacent pairs
        __builtin_memcpy(t,  p,           8);    // 8B load, any 4B alignment ok
        __builtin_memcpy(bt, p + IN_SIZE, 8);
        const float res = t[0] * W00 + t[1] * W01 + bt[0] * W10 + bt[1] * W11;
        // streaming store: coalesced across lanes (consecutive j)
        __builtin_nontemporal_store(res, out + out_base + (size_t)ch * OUT_SIZE * OUT_SIZE);
    }
}

extern "C" void kernel_launch(void* const* d_in, const int* in_sizes, int n_in,
                              void* d_out, int out_size, void* d_ws, size_t ws_size,
                              hipStream_t stream) {
    const float* images = (const float*)d_in[0];   // [64,3,448,448] f32
    const float* locs   = (const float*)d_in[1];   // [64,3] f32
    float* out = (float*)d_out;                    // [64,3,224,224] f32

    const int B = in_sizes[1] / 3;                 // 64
    const int total = B * PX_PER_SAMPLE;           // 3.2M threads, 1 px each
    const int block = 256;
    const int grid = (total + block - 1) / block;  // 12544 (div by 8)
    attention_crop_kernel<<<grid, block, 0, stream>>>(images, locs, out);
}